// Round 1
// baseline (3438.570 us; speedup 1.0000x reference)
//
#include <hip/hip_runtime.h>

#define N_NODES 100000
#define N_EDGES 3200000
#define IN_DIM 6
#define HID_DIM 32
#define LAT_DIM 16

// ---------------- degree ----------------
__global__ void k_deg(const int* __restrict__ dst, unsigned* __restrict__ deg, int E) {
    int e = blockIdx.x * blockDim.x + threadIdx.x;
    if (e < E) atomicAdd(&deg[dst[e]], 1u);
}

__global__ void k_dinv(const unsigned* __restrict__ deg, float* __restrict__ dinv, int N) {
    int i = blockIdx.x * blockDim.x + threadIdx.x;
    if (i < N) dinv[i] = rsqrtf((float)(deg[i] + 1u));  // +1 self-loop; always >= 1
}

// ---------------- layer 1 transform: h1s[i] = (x[i] @ W1) * dinv[i] ----------------
__global__ void k_xw1(const float* __restrict__ x, const float* __restrict__ W1,
                      const float* __restrict__ dinv, float* __restrict__ h1s, int N) {
    __shared__ float w[IN_DIM * HID_DIM];
    for (int t = threadIdx.x; t < IN_DIM * HID_DIM; t += blockDim.x) w[t] = W1[t];
    __syncthreads();
    int i = blockIdx.x * blockDim.x + threadIdx.x;
    if (i >= N) return;
    float xi[IN_DIM];
#pragma unroll
    for (int k = 0; k < IN_DIM; k++) xi[k] = x[(size_t)i * IN_DIM + k];
    float dv = dinv[i];
    float out[HID_DIM];
#pragma unroll
    for (int c = 0; c < HID_DIM; c++) {
        float a = 0.f;
#pragma unroll
        for (int k = 0; k < IN_DIM; k++) a += xi[k] * w[k * HID_DIM + c];
        out[c] = a * dv;
    }
    float4* dsto = (float4*)(h1s + (size_t)i * HID_DIM);
#pragma unroll
    for (int q = 0; q < HID_DIM / 4; q++)
        dsto[q] = make_float4(out[4 * q], out[4 * q + 1], out[4 * q + 2], out[4 * q + 3]);
}

// ---------------- layer-1 edge scatter: A1[dst] += h1s[src], 4 threads/edge x 8 cols ----------------
__global__ void k_scat1(const int* __restrict__ src, const int* __restrict__ dst,
                        const float* __restrict__ h1s, float* __restrict__ A1, int E) {
    int tid = blockIdx.x * blockDim.x + threadIdx.x;
    int e = tid >> 2;
    if (e >= E) return;
    int p = tid & 3;  // 8 columns per part
    int s = src[e], d = dst[e];
    const float4* hp = (const float4*)(h1s + (size_t)s * HID_DIM + p * 8);
    float4 a = hp[0], b = hp[1];
    float* o = A1 + (size_t)d * HID_DIM + p * 8;
    unsafeAtomicAdd(o + 0, a.x);
    unsafeAtomicAdd(o + 1, a.y);
    unsafeAtomicAdd(o + 2, a.z);
    unsafeAtomicAdd(o + 3, a.w);
    unsafeAtomicAdd(o + 4, b.x);
    unsafeAtomicAdd(o + 5, b.y);
    unsafeAtomicAdd(o + 6, b.z);
    unsafeAtomicAdd(o + 7, b.w);
}

// ---------------- mid: act = relu(dinv*(A1+h1s)+b1); h2s = (act @ W2) * dinv ----------------
__global__ void k_mid(const float* __restrict__ A1, const float* __restrict__ h1s,
                      const float* __restrict__ dinv, const float* __restrict__ b1,
                      const float* __restrict__ W2, float* __restrict__ h2s, int N) {
    __shared__ float w[HID_DIM * LAT_DIM];
    __shared__ float bs[HID_DIM];
    for (int t = threadIdx.x; t < HID_DIM * LAT_DIM; t += blockDim.x) w[t] = W2[t];
    if (threadIdx.x < HID_DIM) bs[threadIdx.x] = b1[threadIdx.x];
    __syncthreads();
    int i = blockIdx.x * blockDim.x + threadIdx.x;
    if (i >= N) return;
    float dv = dinv[i];
    float act[HID_DIM];
    const float4* ap = (const float4*)(A1 + (size_t)i * HID_DIM);
    const float4* hp = (const float4*)(h1s + (size_t)i * HID_DIM);
#pragma unroll
    for (int q = 0; q < HID_DIM / 4; q++) {
        float4 a = ap[q], h = hp[q];
        act[4 * q + 0] = fmaxf(dv * (a.x + h.x) + bs[4 * q + 0], 0.f);
        act[4 * q + 1] = fmaxf(dv * (a.y + h.y) + bs[4 * q + 1], 0.f);
        act[4 * q + 2] = fmaxf(dv * (a.z + h.z) + bs[4 * q + 2], 0.f);
        act[4 * q + 3] = fmaxf(dv * (a.w + h.w) + bs[4 * q + 3], 0.f);
    }
    float out[LAT_DIM];
#pragma unroll
    for (int c = 0; c < LAT_DIM; c++) {
        float z = 0.f;
#pragma unroll
        for (int k = 0; k < HID_DIM; k++) z += act[k] * w[k * LAT_DIM + c];
        out[c] = z * dv;
    }
    float4* dsto = (float4*)(h2s + (size_t)i * LAT_DIM);
#pragma unroll
    for (int q = 0; q < LAT_DIM / 4; q++)
        dsto[q] = make_float4(out[4 * q], out[4 * q + 1], out[4 * q + 2], out[4 * q + 3]);
}

// ---------------- layer-2 edge scatter: A2[dst] += h2s[src], 4 threads/edge x 4 cols ----------------
__global__ void k_scat2(const int* __restrict__ src, const int* __restrict__ dst,
                        const float* __restrict__ h2s, float* __restrict__ A2, int E) {
    int tid = blockIdx.x * blockDim.x + threadIdx.x;
    int e = tid >> 2;
    if (e >= E) return;
    int p = tid & 3;  // 4 columns per part
    int s = src[e], d = dst[e];
    const float4* hp = (const float4*)(h2s + (size_t)s * LAT_DIM + p * 4);
    float4 a = hp[0];
    float* o = A2 + (size_t)d * LAT_DIM + p * 4;
    unsafeAtomicAdd(o + 0, a.x);
    unsafeAtomicAdd(o + 1, a.y);
    unsafeAtomicAdd(o + 2, a.z);
    unsafeAtomicAdd(o + 3, a.w);
}

// ---------------- finalize: out = dinv*(A2+h2s) + b2 ----------------
__global__ void k_fin(const float* __restrict__ A2, const float* __restrict__ h2s,
                      const float* __restrict__ dinv, const float* __restrict__ b2,
                      float* __restrict__ out, int N) {
    int idx = blockIdx.x * blockDim.x + threadIdx.x;
    if (idx >= N * LAT_DIM) return;
    int n = idx >> 4, c = idx & (LAT_DIM - 1);
    out[idx] = dinv[n] * (A2[idx] + h2s[idx]) + b2[c];
}

extern "C" void kernel_launch(void* const* d_in, const int* in_sizes, int n_in,
                              void* d_out, int out_size, void* d_ws, size_t ws_size,
                              hipStream_t stream) {
    const float* x  = (const float*)d_in[0];
    const int*   ei = (const int*)d_in[1];
    const float* W1 = (const float*)d_in[2];
    const float* b1 = (const float*)d_in[3];
    const float* W2 = (const float*)d_in[4];
    const float* b2 = (const float*)d_in[5];
    float* out = (float*)d_out;

    const int N = N_NODES, E = N_EDGES;
    const int* src = ei;       // edge_index[0]
    const int* dst = ei + E;   // edge_index[1]

    // workspace carve (256B aligned)
    char* ws = (char*)d_ws;
    size_t off = 0;
    auto take = [&](size_t bytes) -> void* {
        void* p = ws + off;
        off += (bytes + 255) & ~(size_t)255;
        return p;
    };
    unsigned* deg  = (unsigned*)take((size_t)N * 4);
    float*    dinv = (float*)take((size_t)N * 4);
    float*    h1s  = (float*)take((size_t)N * HID_DIM * 4);
    float*    A1   = (float*)take((size_t)N * HID_DIM * 4);
    float*    h2s  = (float*)take((size_t)N * LAT_DIM * 4);
    float*    A2   = (float*)take((size_t)N * LAT_DIM * 4);

    hipMemsetAsync(deg, 0, (size_t)N * 4, stream);
    hipMemsetAsync(A1, 0, (size_t)N * HID_DIM * 4, stream);
    hipMemsetAsync(A2, 0, (size_t)N * LAT_DIM * 4, stream);

    const int B = 256;
    k_deg<<<(E + B - 1) / B, B, 0, stream>>>(dst, deg, E);
    k_dinv<<<(N + B - 1) / B, B, 0, stream>>>(deg, dinv, N);
    k_xw1<<<(N + B - 1) / B, B, 0, stream>>>(x, W1, dinv, h1s, N);
    k_scat1<<<((E * 4) + B - 1) / B, B, 0, stream>>>(src, dst, h1s, A1, E);
    k_mid<<<(N + B - 1) / B, B, 0, stream>>>(A1, h1s, dinv, b1, W2, h2s, N);
    k_scat2<<<((E * 4) + B - 1) / B, B, 0, stream>>>(src, dst, h2s, A2, E);
    k_fin<<<((N * LAT_DIM) + B - 1) / B, B, 0, stream>>>(A2, h2s, dinv, b2, out, N);
}

// Round 2
// 750.771 us; speedup vs baseline: 4.5801x; 4.5801x over previous
//
#include <hip/hip_runtime.h>

#define N_NODES 100000
#define N_EDGES 3200000
#define IN_DIM 6
#define HID_DIM 32
#define LAT_DIM 16
#define SCAN_T 1024

// ---------------- degree histogram (int atomics, L2-served) ----------------
__global__ void k_deg(const int* __restrict__ dst, int* __restrict__ deg, int E) {
    int e = blockIdx.x * blockDim.x + threadIdx.x;
    if (e < E) atomicAdd(&deg[dst[e]], 1);
}

__global__ void k_dinv(const int* __restrict__ deg, float* __restrict__ dinv, int N) {
    int i = blockIdx.x * blockDim.x + threadIdx.x;
    if (i < N) dinv[i] = rsqrtf((float)(deg[i] + 1));  // +1 self-loop; always >= 1
}

// ---------------- exclusive scan of deg -> rowptr, cursor (single block) ----------------
__global__ void k_scan(const int* __restrict__ deg, int* __restrict__ rowptr,
                       int* __restrict__ cursor, int N) {
    __shared__ int sums[SCAN_T];
    int t = threadIdx.x;
    int chunk = (N + SCAN_T - 1) / SCAN_T;
    int beg = t * chunk;
    int end = beg + chunk; if (end > N) end = N;
    int s = 0;
    for (int i = beg; i < end && i < N; i++) s += deg[i];
    sums[t] = s;
    __syncthreads();
    // Hillis-Steele inclusive scan
    for (int off = 1; off < SCAN_T; off <<= 1) {
        int v = (t >= off) ? sums[t - off] : 0;
        __syncthreads();
        sums[t] += v;
        __syncthreads();
    }
    int run = (t == 0) ? 0 : sums[t - 1];
    for (int i = beg; i < end && i < N; i++) {
        rowptr[i] = run;
        cursor[i] = run;
        run += deg[i];
    }
    if (t == SCAN_T - 1) rowptr[N] = sums[SCAN_T - 1];  // == E
}

// ---------------- place edges: perm[] holds src sorted by dst ----------------
__global__ void k_place(const int* __restrict__ src, const int* __restrict__ dst,
                        int* __restrict__ cursor, int* __restrict__ perm, int E) {
    int e = blockIdx.x * blockDim.x + threadIdx.x;
    if (e < E) {
        int pos = atomicAdd(&cursor[dst[e]], 1);
        perm[pos] = src[e];
    }
}

// ---------------- layer 1 transform: h1s[i] = (x[i] @ W1) * dinv[i] ----------------
__global__ void k_xw1(const float* __restrict__ x, const float* __restrict__ W1,
                      const float* __restrict__ dinv, float* __restrict__ h1s, int N) {
    __shared__ float w[IN_DIM * HID_DIM];
    for (int t = threadIdx.x; t < IN_DIM * HID_DIM; t += blockDim.x) w[t] = W1[t];
    __syncthreads();
    int i = blockIdx.x * blockDim.x + threadIdx.x;
    if (i >= N) return;
    float xi[IN_DIM];
#pragma unroll
    for (int k = 0; k < IN_DIM; k++) xi[k] = x[(size_t)i * IN_DIM + k];
    float dv = dinv[i];
    float out[HID_DIM];
#pragma unroll
    for (int c = 0; c < HID_DIM; c++) {
        float a = 0.f;
#pragma unroll
        for (int k = 0; k < IN_DIM; k++) a += xi[k] * w[k * HID_DIM + c];
        out[c] = a * dv;
    }
    float4* dsto = (float4*)(h1s + (size_t)i * HID_DIM);
#pragma unroll
    for (int q = 0; q < HID_DIM / 4; q++)
        dsto[q] = make_float4(out[4 * q], out[4 * q + 1], out[4 * q + 2], out[4 * q + 3]);
}

// ---------------- layer-1 gather-aggregate + bias + relu: 8 threads/node ----------------
__global__ void k_agg1(const int* __restrict__ rowptr, const int* __restrict__ perm,
                       const float* __restrict__ h1s, const float* __restrict__ dinv,
                       const float* __restrict__ b1, float* __restrict__ act, int N) {
    int t = blockIdx.x * blockDim.x + threadIdx.x;
    int node = t >> 3, p = t & 7;
    if (node >= N) return;
    int beg = rowptr[node], end = rowptr[node + 1];
    float4 acc = make_float4(0.f, 0.f, 0.f, 0.f);
    for (int k = beg; k < end; k++) {
        int s = perm[k];
        float4 h = *(const float4*)(h1s + (size_t)s * HID_DIM + p * 4);
        acc.x += h.x; acc.y += h.y; acc.z += h.z; acc.w += h.w;
    }
    float4 hs = *(const float4*)(h1s + (size_t)node * HID_DIM + p * 4);  // self-loop
    float dv = dinv[node];
    float4 bb = *(const float4*)(b1 + p * 4);
    float4 o;
    o.x = fmaxf(dv * (acc.x + hs.x) + bb.x, 0.f);
    o.y = fmaxf(dv * (acc.y + hs.y) + bb.y, 0.f);
    o.z = fmaxf(dv * (acc.z + hs.z) + bb.z, 0.f);
    o.w = fmaxf(dv * (acc.w + hs.w) + bb.w, 0.f);
    *(float4*)(act + (size_t)node * HID_DIM + p * 4) = o;
}

// ---------------- layer 2 transform: h2s[i] = (act[i] @ W2) * dinv[i] ----------------
__global__ void k_h2(const float* __restrict__ act, const float* __restrict__ W2,
                     const float* __restrict__ dinv, float* __restrict__ h2s, int N) {
    __shared__ float w[HID_DIM * LAT_DIM];
    for (int t = threadIdx.x; t < HID_DIM * LAT_DIM; t += blockDim.x) w[t] = W2[t];
    __syncthreads();
    int i = blockIdx.x * blockDim.x + threadIdx.x;
    if (i >= N) return;
    float a[HID_DIM];
    const float4* ap = (const float4*)(act + (size_t)i * HID_DIM);
#pragma unroll
    for (int q = 0; q < HID_DIM / 4; q++) {
        float4 v = ap[q];
        a[4 * q] = v.x; a[4 * q + 1] = v.y; a[4 * q + 2] = v.z; a[4 * q + 3] = v.w;
    }
    float dv = dinv[i];
    float out[LAT_DIM];
#pragma unroll
    for (int c = 0; c < LAT_DIM; c++) {
        float z = 0.f;
#pragma unroll
        for (int k = 0; k < HID_DIM; k++) z += a[k] * w[k * LAT_DIM + c];
        out[c] = z * dv;
    }
    float4* dsto = (float4*)(h2s + (size_t)i * LAT_DIM);
#pragma unroll
    for (int q = 0; q < LAT_DIM / 4; q++)
        dsto[q] = make_float4(out[4 * q], out[4 * q + 1], out[4 * q + 2], out[4 * q + 3]);
}

// ---------------- layer-2 gather-aggregate + bias -> out: 4 threads/node ----------------
__global__ void k_agg2(const int* __restrict__ rowptr, const int* __restrict__ perm,
                       const float* __restrict__ h2s, const float* __restrict__ dinv,
                       const float* __restrict__ b2, float* __restrict__ out, int N) {
    int t = blockIdx.x * blockDim.x + threadIdx.x;
    int node = t >> 2, p = t & 3;
    if (node >= N) return;
    int beg = rowptr[node], end = rowptr[node + 1];
    float4 acc = make_float4(0.f, 0.f, 0.f, 0.f);
    for (int k = beg; k < end; k++) {
        int s = perm[k];
        float4 h = *(const float4*)(h2s + (size_t)s * LAT_DIM + p * 4);
        acc.x += h.x; acc.y += h.y; acc.z += h.z; acc.w += h.w;
    }
    float4 hs = *(const float4*)(h2s + (size_t)node * LAT_DIM + p * 4);  // self-loop
    float dv = dinv[node];
    float4 bb = *(const float4*)(b2 + p * 4);
    float4 o;
    o.x = dv * (acc.x + hs.x) + bb.x;
    o.y = dv * (acc.y + hs.y) + bb.y;
    o.z = dv * (acc.z + hs.z) + bb.z;
    o.w = dv * (acc.w + hs.w) + bb.w;
    *(float4*)(out + (size_t)node * LAT_DIM + p * 4) = o;
}

extern "C" void kernel_launch(void* const* d_in, const int* in_sizes, int n_in,
                              void* d_out, int out_size, void* d_ws, size_t ws_size,
                              hipStream_t stream) {
    const float* x  = (const float*)d_in[0];
    const int*   ei = (const int*)d_in[1];
    const float* W1 = (const float*)d_in[2];
    const float* b1 = (const float*)d_in[3];
    const float* W2 = (const float*)d_in[4];
    const float* b2 = (const float*)d_in[5];
    float* out = (float*)d_out;

    const int N = N_NODES, E = N_EDGES;
    const int* src = ei;       // edge_index[0]
    const int* dst = ei + E;   // edge_index[1]

    // workspace carve (256B aligned)
    char* ws = (char*)d_ws;
    size_t off = 0;
    auto take = [&](size_t bytes) -> void* {
        void* p = ws + off;
        off += (bytes + 255) & ~(size_t)255;
        return p;
    };
    int*   deg    = (int*)take((size_t)N * 4);
    float* dinv   = (float*)take((size_t)N * 4);
    int*   rowptr = (int*)take((size_t)(N + 1) * 4);
    int*   cursor = (int*)take((size_t)N * 4);
    int*   perm   = (int*)take((size_t)E * 4);
    float* h1s    = (float*)take((size_t)N * HID_DIM * 4);
    float* act    = (float*)take((size_t)N * HID_DIM * 4);
    float* h2s    = h1s;  // h1s dead after k_agg1; reuse its space

    hipMemsetAsync(deg, 0, (size_t)N * 4, stream);

    const int B = 256;
    k_deg<<<(E + B - 1) / B, B, 0, stream>>>(dst, deg, E);
    k_dinv<<<(N + B - 1) / B, B, 0, stream>>>(deg, dinv, N);
    k_scan<<<1, SCAN_T, 0, stream>>>(deg, rowptr, cursor, N);
    k_place<<<(E + B - 1) / B, B, 0, stream>>>(src, dst, cursor, perm, E);
    k_xw1<<<(N + B - 1) / B, B, 0, stream>>>(x, W1, dinv, h1s, N);
    k_agg1<<<((N * 8) + B - 1) / B, B, 0, stream>>>(rowptr, perm, h1s, dinv, b1, act, N);
    k_h2<<<(N + B - 1) / B, B, 0, stream>>>(act, W2, dinv, h2s, N);
    k_agg2<<<((N * 4) + B - 1) / B, B, 0, stream>>>(rowptr, perm, h2s, dinv, b2, out, N);
}